// Round 11
// baseline (529.537 us; speedup 1.0000x reference)
//
#include <hip/hip_runtime.h>
#include <math.h>

#define NN 50000
#define NE 600000
#define DIM 128
#define NLAYERS 7
#define LDK 136           // padded LDS row stride in shorts (272B = 17*16B, keeps uint4 aligned)
#define LDF 132           // padded f32 row stride for the act-transpose staging
#define BN_EPS 1e-5f
#define GB 782            // mlp blocks per layer (ceil(50000/64))
#define PART_SLOT 200192  // GB*256 floats per layer slot

typedef __attribute__((ext_vector_type(4))) float floatx4;
typedef __attribute__((ext_vector_type(8))) _Float16 half8;
typedef __attribute__((ext_vector_type(2))) _Float16 half2v;

__device__ __forceinline__ unsigned short f2h(float f) {
  _Float16 h = (_Float16)f;  // v_cvt_f16_f32, RTNE
  return __builtin_bit_cast(unsigned short, h);
}
__device__ __forceinline__ float2 up(unsigned int u) {
  half2v h = __builtin_bit_cast(half2v, u);
  return make_float2((float)h.x, (float)h.y);
}
__device__ __forceinline__ unsigned int pk(float a, float b) {
  half2v h;
  h.x = (_Float16)a;
  h.y = (_Float16)b;
  return __builtin_bit_cast(unsigned int, h);
}
// tanh(x) = 1 - 2/(e^{2x}+1); exp->v_exp_f32, rcp->v_rcp_f32. Saturates to +-1 correctly.
__device__ __forceinline__ float tanh_fast(float x) {
  float e = __expf(2.0f * x);
  return 1.0f - 2.0f * __builtin_amdgcn_rcpf(e + 1.0f);
}

// ---------------- CSR build ----------------

__global__ void hist_kernel(const int* __restrict__ ei, int* __restrict__ deg) {
  int e = blockIdx.x * 256 + threadIdx.x;
  if (e < NE) atomicAdd(&deg[ei[NE + e]], 1);
}

__global__ __launch_bounds__(256) void scan_part(const int* __restrict__ deg,
                                                 int* __restrict__ rowl,
                                                 int* __restrict__ bsum) {
  int b = blockIdx.x, t = threadIdx.x;
  int base = b * 1024 + t * 4;
  int d[4];
  #pragma unroll
  for (int j = 0; j < 4; j++) d[j] = (base + j < NN) ? deg[base + j] : 0;
  int s = d[0] + d[1] + d[2] + d[3];
  int lane = t & 63;
  int incl = s;
  #pragma unroll
  for (int off = 1; off < 64; off <<= 1) {
    int n = __shfl_up(incl, off);
    if (lane >= off) incl += n;
  }
  __shared__ int wtot[4];
  if (lane == 63) wtot[t >> 6] = incl;
  __syncthreads();
  int woff = 0;
  for (int w = 0; w < (t >> 6); w++) woff += wtot[w];
  int run = woff + incl - s;
  #pragma unroll
  for (int j = 0; j < 4; j++) {
    if (base + j < NN) rowl[base + j] = run;
    run += d[j];
  }
  if (t == 255) bsum[b] = woff + incl;
}

__global__ void scan_top(const int* __restrict__ bsum, int* __restrict__ boff,
                         int* __restrict__ row) {
  int t = threadIdx.x;  // one wave
  int v = (t < 49) ? bsum[t] : 0;
  int incl = v;
  #pragma unroll
  for (int off = 1; off < 64; off <<= 1) {
    int n = __shfl_up(incl, off);
    if (t >= off) incl += n;
  }
  if (t < 49) boff[t] = incl - v;
  if (t == 48) row[NN] = incl;
}

__global__ __launch_bounds__(256) void scan_apply(const int* __restrict__ rowl,
                                                  const int* __restrict__ boff,
                                                  int* __restrict__ row,
                                                  int* __restrict__ cur) {
  int i = blockIdx.x * 256 + threadIdx.x;
  if (i < NN) {
    int r = rowl[i] + boff[i >> 10];
    row[i] = r;
    cur[i] = r;
  }
}

__global__ void bucket_kernel(const int* __restrict__ ei, int* __restrict__ cur,
                              int* __restrict__ esrc) {
  int e = blockIdx.x * 256 + threadIdx.x;
  if (e < NE) {
    int d = ei[NE + e];
    int p = atomicAdd(&cur[d], 1);
    esrc[p] = ei[e];
  }
}

// ---------------- converts ----------------

__global__ void convw_kernel(const float* __restrict__ W1, const float* __restrict__ W2,
                             unsigned short* __restrict__ wb) {
  int i = blockIdx.x * 256 + threadIdx.x;  // 7*16384
  if (i >= NLAYERS * 16384) return;
  int l = i >> 14;
  int r = i & 16383;
  int n = r >> 7;
  int k = r & 127;
  wb[(size_t)(l * 2 + 0) * 16384 + n * 128 + k] = f2h(W1[(size_t)l * 16384 + k * 128 + n]);
  wb[(size_t)(l * 2 + 1) * 16384 + n * 128 + k] = f2h(W2[(size_t)l * 16384 + k * 128 + n]);
}

__global__ __launch_bounds__(256) void convx_kernel(const float* __restrict__ x,
                                                    unsigned int* __restrict__ x16) {
  int i = blockIdx.x * 256 + threadIdx.x;  // 1.6M exact
  float4 v = ((const float4*)x)[i];
  uint2 o;
  o.x = pk(v.x, v.y);
  o.y = pk(v.z, v.w);
  ((uint2*)x16)[i] = o;
}

// ---------------- gather (fp16): agg16[n] = sum_{e in CSR[n]} x16[esrc[e]] ----------------
// uint4 edge-slot gather (r9-proven): lane = (edge-slot g = lane>>4, 16B chunk c = lane&15),
// 4 edges/VMEM inst, 8 edges in flight; cross-slot reduce via shfl_xor(16/32).

__global__ __launch_bounds__(256) void gather_kernel(
    const unsigned int* __restrict__ x16, const int* __restrict__ esrc,
    const int* __restrict__ row, unsigned int* __restrict__ agg16) {
  int w = (blockIdx.x * 256 + threadIdx.x) >> 6;  // one wave per node
  int lane = threadIdx.x & 63;
  if (w >= NN) return;
  int g = lane >> 4;  // edge slot 0..3
  int c = lane & 15;  // uint4 chunk within row
  int s0 = row[w], s1 = row[w + 1];
  const uint4* xv4 = (const uint4*)x16;
  float a0 = 0.f, a1 = 0.f, a2 = 0.f, a3 = 0.f, a4 = 0.f, a5 = 0.f, a6 = 0.f, a7 = 0.f;
  int e = s0;
  for (; e + 7 < s1; e += 8) {  // 8 edges in flight (2 x 4-slot groups)
    int i0 = esrc[e + g];
    int i1 = esrc[e + 4 + g];
    uint4 v0 = xv4[(size_t)i0 * 16 + c];
    uint4 v1 = xv4[(size_t)i1 * 16 + c];
    float2 f;
    f = up(v0.x); a0 += f.x; a1 += f.y;
    f = up(v0.y); a2 += f.x; a3 += f.y;
    f = up(v0.z); a4 += f.x; a5 += f.y;
    f = up(v0.w); a6 += f.x; a7 += f.y;
    f = up(v1.x); a0 += f.x; a1 += f.y;
    f = up(v1.y); a2 += f.x; a3 += f.y;
    f = up(v1.z); a4 += f.x; a5 += f.y;
    f = up(v1.w); a6 += f.x; a7 += f.y;
  }
  for (; e < s1; e += 4) {  // masked 4-slot tail
    int ee = e + g;
    bool val = ee < s1;
    int idx = esrc[val ? ee : s0];
    uint4 v = xv4[(size_t)idx * 16 + c];
    if (!val) { v.x = 0u; v.y = 0u; v.z = 0u; v.w = 0u; }
    float2 f;
    f = up(v.x); a0 += f.x; a1 += f.y;
    f = up(v.y); a2 += f.x; a3 += f.y;
    f = up(v.z); a4 += f.x; a5 += f.y;
    f = up(v.w); a6 += f.x; a7 += f.y;
  }
  // reduce across edge slots: lanes {c, c+16, c+32, c+48}
  a0 += __shfl_xor(a0, 16); a0 += __shfl_xor(a0, 32);
  a1 += __shfl_xor(a1, 16); a1 += __shfl_xor(a1, 32);
  a2 += __shfl_xor(a2, 16); a2 += __shfl_xor(a2, 32);
  a3 += __shfl_xor(a3, 16); a3 += __shfl_xor(a3, 32);
  a4 += __shfl_xor(a4, 16); a4 += __shfl_xor(a4, 32);
  a5 += __shfl_xor(a5, 16); a5 += __shfl_xor(a5, 32);
  a6 += __shfl_xor(a6, 16); a6 += __shfl_xor(a6, 32);
  a7 += __shfl_xor(a7, 16); a7 += __shfl_xor(a7, 32);
  if (lane < 16) {
    uint4 o;
    o.x = pk(a0, a1);
    o.y = pk(a2, a3);
    o.z = pk(a4, a5);
    o.w = pk(a6, a7);
    ((uint4*)agg16)[(size_t)w * 16 + c] = o;
  }
}

// ---------------- single-layer MLP (layers 0-2), fp16 in/out, BN-prev folded ----------------
// r9-proven config (LDK=136, full-128-row wS, 3 blocks/CU, vectorized epilogue) + W2
// register prefetch: W2's 32 loads issue at kernel start and land under h/W1 staging +
// GEMM1, so the W2 stage phase is a pure reg->LDS write (no exposed load latency).

__global__ __launch_bounds__(256) void mlp1_kernel(
    const unsigned int* __restrict__ x16, const unsigned int* __restrict__ agg16,
    const unsigned short* __restrict__ wb,  // this layer's [2][128][128] fp16 [n][k]
    const float* __restrict__ b1, const float* __restrict__ b2,
    unsigned short* __restrict__ xout16, float* __restrict__ part,
    const float* __restrict__ bnPrev, const float* __restrict__ gPrev,
    const float* __restrict__ btPrev, const int* __restrict__ deg, int hasPrev) {
  __shared__ unsigned short hS[64 * LDK];
  __shared__ unsigned short wS[128 * LDK];
  __shared__ float scshS[256];
  int tid = threadIdx.x;
  int row0 = blockIdx.x * 64;

  if (tid < 128) {
    float sc = 1.f, sh = 0.f;
    if (hasPrev) {
      const float inv = 1.f / (float)NN;
      float mean = bnPrev[tid] * inv;
      float var = bnPrev[128 + tid] * inv - mean * mean;
      sc = gPrev[tid] * rsqrtf(var + BN_EPS);
      sh = btPrev[tid] - mean * sc;
    }
    scshS[tid] = sc;
    scshS[128 + tid] = sh;
  }

  // prefetch W2 into regs; lands under h/W1 staging + GEMM1
  uint4 w2reg[8];
  #pragma unroll
  for (int j = 0; j < 8; j++) {
    int q = tid + j * 256;
    w2reg[j] = *(const uint4*)(wb + 16384 + (q >> 4) * 128 + (q & 15) * 8);
  }
  __syncthreads();  // scshS visible

  // stage h = sc*(x+agg) + (1+deg)*sh -> fp16 LDS, 16B/thread
  for (int idx = tid; idx < 1024; idx += 256) {
    int r = idx >> 4;
    int c = (idx & 15) * 8;  // half index
    uint4 hv = {0u, 0u, 0u, 0u};
    if (row0 + r < NN) {
      size_t base = (size_t)(row0 + r) * 16 + (c >> 3);
      uint4 xv = ((const uint4*)x16)[base];
      uint4 av = ((const uint4*)agg16)[base];
      float dr = 1.f + (float)deg[row0 + r];
      unsigned int xs[4] = {xv.x, xv.y, xv.z, xv.w};
      unsigned int as_[4] = {av.x, av.y, av.z, av.w};
      unsigned int hs[4];
      #pragma unroll
      for (int j = 0; j < 4; j++) {
        float2 xf = up(xs[j]);
        float2 af = up(as_[j]);
        int cc = c + j * 2;
        float h0 = scshS[cc] * (xf.x + af.x) + dr * scshS[128 + cc];
        float h1 = scshS[cc + 1] * (xf.y + af.y) + dr * scshS[128 + cc + 1];
        hs[j] = pk(h0, h1);
      }
      hv.x = hs[0]; hv.y = hs[1]; hv.z = hs[2]; hv.w = hs[3];
    }
    *(uint4*)&hS[r * LDK + c] = hv;
  }
  for (int q = tid; q < 2048; q += 256) {
    int rw = q >> 4;
    int c8 = (q & 15) * 8;
    *(uint4*)&wS[rw * LDK + c8] = *(const uint4*)(wb + rw * 128 + c8);
  }
  __syncthreads();

  int lane = tid & 63;
  int wav = tid >> 6;
  int quad = lane >> 4;
  int lm = lane & 15;
  int mrow = wav * 16 + lm;
  bool wvalid = (row0 + wav * 16) < NN;

  half8 aF[4];
  #pragma unroll
  for (int ks = 0; ks < 4; ks++)
    aF[ks] = *(half8*)&hS[mrow * LDK + ks * 32 + quad * 8];

  floatx4 acc[8];
  #pragma unroll
  for (int nt = 0; nt < 8; nt++) {
    float bv = b1[nt * 16 + lm];
    floatx4 c = {bv, bv, bv, bv};
    #pragma unroll
    for (int ks = 0; ks < 4; ks++) {
      half8 bf = *(half8*)&wS[(nt * 16 + lm) * LDK + ks * 32 + quad * 8];
      c = __builtin_amdgcn_mfma_f32_16x16x32_f16(aF[ks], bf, c, 0, 0, 0);
    }
    acc[nt] = c;
  }
  #pragma unroll
  for (int nt = 0; nt < 8; nt++) {
    #pragma unroll
    for (int rg = 0; rg < 4; rg++) {
      float v = acc[nt][rg];
      v = v > 0.f ? v : 0.f;
      hS[(wav * 16 + quad * 4 + rg) * LDK + nt * 16 + lm] = f2h(v);
    }
  }
  __syncthreads();  // wS(W1) reads + h1 writes done
  // W2 stage = pure reg->LDS write (loads landed long ago)
  #pragma unroll
  for (int j = 0; j < 8; j++) {
    int q = tid + j * 256;
    *(uint4*)&wS[(q >> 4) * LDK + (q & 15) * 8] = w2reg[j];
  }
  __syncthreads();

  // cache h1 A-fragments, then ALL GEMM2 (so hS/wS free for epilogue staging)
  half8 aG[4];
  #pragma unroll
  for (int ks = 0; ks < 4; ks++)
    aG[ks] = *(half8*)&hS[mrow * LDK + ks * 32 + quad * 8];
  #pragma unroll
  for (int nt = 0; nt < 8; nt++) {
    float bv = b2[nt * 16 + lm];
    floatx4 c = {bv, bv, bv, bv};
    #pragma unroll
    for (int ks = 0; ks < 4; ks++) {
      half8 bf = *(half8*)&wS[(nt * 16 + lm) * LDK + ks * 32 + quad * 8];
      c = __builtin_amdgcn_mfma_f32_16x16x32_f16(aG[ks], bf, c, 0, 0, 0);
    }
    acc[nt] = c;
  }

  float sArr[8], sqArr[8];
  #pragma unroll
  for (int nt = 0; nt < 8; nt++) {
    float s = 0.f, sq = 0.f;
    #pragma unroll
    for (int rg = 0; rg < 4; rg++) {
      float v = acc[nt][rg];
      v = v > 0.f ? v : 0.f;
      acc[nt][rg] = v;
      s += v;
      sq += v * v;
    }
    s += __shfl_xor(s, 16);
    s += __shfl_xor(s, 32);
    sq += __shfl_xor(sq, 16);
    sq += __shfl_xor(sq, 32);
    sArr[nt] = s;
    sqArr[nt] = sq;
  }
  __syncthreads();  // all wS(W2) + hS(h1) reads done

  // stage fp16 output into hS; redS into wS (free)
  #pragma unroll
  for (int nt = 0; nt < 8; nt++) {
    #pragma unroll
    for (int rg = 0; rg < 4; rg++)
      hS[(wav * 16 + quad * 4 + rg) * LDK + nt * 16 + lm] = f2h(acc[nt][rg]);
  }
  float* redW = (float*)wS;
  if (quad == 0) {
    #pragma unroll
    for (int nt = 0; nt < 8; nt++) {
      redW[wav * 256 + nt * 16 + lm] = wvalid ? sArr[nt] : 0.f;
      redW[wav * 256 + 128 + nt * 16 + lm] = wvalid ? sqArr[nt] : 0.f;
    }
  }
  __syncthreads();

  // vectorized store: uint4 per thread, full 256B row segments
  for (int q = tid; q < 1024; q += 256) {
    int rw = q >> 4;
    int c8 = (q & 15) * 8;
    if (row0 + rw < NN)
      *(uint4*)&xout16[(size_t)(row0 + rw) * DIM + c8] = *(uint4*)&hS[rw * LDK + c8];
  }
  float v = redW[tid] + redW[256 + tid] + redW[512 + tid] + redW[768 + tid];
  part[(size_t)blockIdx.x * 256 + tid] = v;
}

// ---------------- fused 4-layer MLP (layers 3-6): h staged once, A-frags in regs ----------------
// r9-proven config + rolling weight prefetch: wreg holds the NEXT weight block's 32 loads,
// issued during the current GEMM; each stage phase is a pure reg->LDS write.

__global__ __launch_bounds__(256) void mlp4_kernel(
    const unsigned int* __restrict__ x16, const unsigned int* __restrict__ agg16,
    const unsigned short* __restrict__ wbg,
    const float* __restrict__ b1g, const float* __restrict__ b2g,
    float* __restrict__ out, float* __restrict__ partBase,
    const float* __restrict__ bnPrev, const float* __restrict__ gPrev,
    const float* __restrict__ btPrev, const int* __restrict__ deg) {
  __shared__ unsigned short hS[64 * LDK];
  __shared__ unsigned short wS[128 * LDK];
  __shared__ float scshS[256];
  int tid = threadIdx.x;
  int row0 = blockIdx.x * 64;

  if (tid < 128) {
    const float inv = 1.f / (float)NN;
    float mean = bnPrev[tid] * inv;
    float var = bnPrev[128 + tid] * inv - mean * mean;
    float sc = gPrev[tid] * rsqrtf(var + BN_EPS);
    scshS[tid] = sc;
    scshS[128 + tid] = btPrev[tid] - mean * sc;
  }

  // prefetch layer-3 W1 into regs; lands under h staging
  uint4 wreg[8];
  #pragma unroll
  for (int j = 0; j < 8; j++) {
    int q = tid + j * 256;
    wreg[j] = *(const uint4*)(wbg + (size_t)3 * 32768 + (q >> 4) * 128 + (q & 15) * 8);
  }
  __syncthreads();  // scshS visible

  for (int idx = tid; idx < 1024; idx += 256) {
    int r = idx >> 4;
    int c = (idx & 15) * 8;
    uint4 hv = {0u, 0u, 0u, 0u};
    if (row0 + r < NN) {
      size_t base = (size_t)(row0 + r) * 16 + (c >> 3);
      uint4 xv = ((const uint4*)x16)[base];
      uint4 av = ((const uint4*)agg16)[base];
      float dr = 1.f + (float)deg[row0 + r];
      unsigned int xs[4] = {xv.x, xv.y, xv.z, xv.w};
      unsigned int as_[4] = {av.x, av.y, av.z, av.w};
      unsigned int hs[4];
      #pragma unroll
      for (int j = 0; j < 4; j++) {
        float2 xf = up(xs[j]);
        float2 af = up(as_[j]);
        int cc = c + j * 2;
        float h0 = scshS[cc] * (xf.x + af.x) + dr * scshS[128 + cc];
        float h1 = scshS[cc + 1] * (xf.y + af.y) + dr * scshS[128 + cc + 1];
        hs[j] = pk(h0, h1);
      }
      hv.x = hs[0]; hv.y = hs[1]; hv.z = hs[2]; hv.w = hs[3];
    }
    *(uint4*)&hS[r * LDK + c] = hv;
  }
  __syncthreads();

  int lane = tid & 63;
  int wav = tid >> 6;
  int quad = lane >> 4;
  int lm = lane & 15;
  int mrow = wav * 16 + lm;
  bool wvalid = (row0 + wav * 16) < NN;

  // A-fragments of h live in registers across all 4 layers
  half8 aF[4];
  #pragma unroll
  for (int ks = 0; ks < 4; ks++)
    aF[ks] = *(half8*)&hS[mrow * LDK + ks * 32 + quad * 8];

  #pragma unroll 1
  for (int ly = 0; ly < 4; ly++) {
    int layer = 3 + ly;
    const unsigned short* wb = wbg + (size_t)layer * 2 * 16384;
    const float* b1 = b1g + layer * 128;
    const float* b2 = b2g + layer * 128;
    float* act = out + (size_t)ly * NN * DIM;
    float* part = partBase + (size_t)ly * PART_SLOT;

    __syncthreads();  // prev iter's wS/hS reads done
    // W1 stage = reg->LDS write; then issue W2 loads (land under GEMM1)
    #pragma unroll
    for (int j = 0; j < 8; j++) {
      int q = tid + j * 256;
      *(uint4*)&wS[(q >> 4) * LDK + (q & 15) * 8] = wreg[j];
    }
    #pragma unroll
    for (int j = 0; j < 8; j++) {
      int q = tid + j * 256;
      wreg[j] = *(const uint4*)(wb + 16384 + (q >> 4) * 128 + (q & 15) * 8);
    }
    __syncthreads();

    floatx4 acc[8];
    #pragma unroll
    for (int nt = 0; nt < 8; nt++) {
      float bv = b1[nt * 16 + lm];
      floatx4 c = {bv, bv, bv, bv};
      #pragma unroll
      for (int ks = 0; ks < 4; ks++) {
        half8 bf = *(half8*)&wS[(nt * 16 + lm) * LDK + ks * 32 + quad * 8];
        c = __builtin_amdgcn_mfma_f32_16x16x32_f16(aF[ks], bf, c, 0, 0, 0);
      }
      acc[nt] = c;
    }
    #pragma unroll
    for (int nt = 0; nt < 8; nt++) {
      #pragma unroll
      for (int rg = 0; rg < 4; rg++) {
        float v = acc[nt][rg];
        v = v > 0.f ? v : 0.f;
        hS[(wav * 16 + quad * 4 + rg) * LDK + nt * 16 + lm] = f2h(v);
      }
    }
    __syncthreads();  // wS(W1) reads + h1 writes done
    // W2 stage = reg->LDS write; then issue next layer's W1 loads (land under GEMM2)
    #pragma unroll
    for (int j = 0; j < 8; j++) {
      int q = tid + j * 256;
      *(uint4*)&wS[(q >> 4) * LDK + (q & 15) * 8] = wreg[j];
    }
    {
      size_t nxt = (ly < 3) ? (size_t)(layer + 1) * 32768 : (size_t)3 * 32768;
      #pragma unroll
      for (int j = 0; j < 8; j++) {
        int q = tid + j * 256;
        wreg[j] = *(const uint4*)(wbg + nxt + (q >> 4) * 128 + (q & 15) * 8);
      }
    }
    __syncthreads();

    // cache h1 A-frags, then ALL GEMM2 (frees hS/wS for epilogue staging)
    half8 aG[4];
    #pragma unroll
    for (int ks = 0; ks < 4; ks++)
      aG[ks] = *(half8*)&hS[mrow * LDK + ks * 32 + quad * 8];
    #pragma unroll
    for (int nt = 0; nt < 8; nt++) {
      float bv = b2[nt * 16 + lm];
      floatx4 c = {bv, bv, bv, bv};
      #pragma unroll
      for (int ks = 0; ks < 4; ks++) {
        half8 bf = *(half8*)&wS[(nt * 16 + lm) * LDK + ks * 32 + quad * 8];
        c = __builtin_amdgcn_mfma_f32_16x16x32_f16(aG[ks], bf, c, 0, 0, 0);
      }
      acc[nt] = c;
    }

    float sArr[8], sqArr[8];
    #pragma unroll
    for (int nt = 0; nt < 8; nt++) {
      float s = 0.f, sq = 0.f;
      #pragma unroll
      for (int rg = 0; rg < 4; rg++) {
        float v = tanh_fast(acc[nt][rg]);
        acc[nt][rg] = v;
        s += v;
        sq += v * v;
      }
      s += __shfl_xor(s, 16);
      s += __shfl_xor(s, 32);
      sq += __shfl_xor(sq, 16);
      sq += __shfl_xor(sq, 32);
      sArr[nt] = s;
      sqArr[nt] = sq;
    }
    __syncthreads();  // all wS(W2) + hS(h1) reads done

    // stage f32 act into wS [64][LDF]; redS into hS (free)
    float* wSf = (float*)wS;
    #pragma unroll
    for (int nt = 0; nt < 8; nt++) {
      #pragma unroll
      for (int rg = 0; rg < 4; rg++)
        wSf[(wav * 16 + quad * 4 + rg) * LDF + nt * 16 + lm] = acc[nt][rg];
    }
    float* redH = (float*)hS;
    if (quad == 0) {
      #pragma unroll
      for (int nt = 0; nt < 8; nt++) {
        redH[wav * 256 + nt * 16 + lm] = wvalid ? sArr[nt] : 0.f;
        redH[wav * 256 + 128 + nt * 16 + lm] = wvalid ? sqArr[nt] : 0.f;
      }
    }
    __syncthreads();

    // vectorized store: float4 per thread, full 512B row segments
    for (int q = tid; q < 2048; q += 256) {
      int rw = q >> 5;
      int c4 = (q & 31) * 4;
      if (row0 + rw < NN)
        *(float4*)&act[(size_t)(row0 + rw) * DIM + c4] = *(float4*)&wSf[rw * LDF + c4];
    }
    float v = redH[tid] + redH[256 + tid] + redH[512 + tid] + redH[768 + tid];
    part[(size_t)blockIdx.x * 256 + tid] = v;
  }
}

// ---------------- fold per-block partials -> bn[256] per layer slot ----------------

__global__ __launch_bounds__(256) void reduce_kernel(const float* __restrict__ part,
                                                     float* __restrict__ bn) {
  int c = blockIdx.x;
  int t = threadIdx.x;
  const float* p = part + (size_t)blockIdx.y * PART_SLOT + c;
  float s = 0.f;
  for (int b = t; b < GB; b += 256) s += p[(size_t)b * 256];
  #pragma unroll
  for (int off = 1; off < 64; off <<= 1) s += __shfl_xor(s, off);
  __shared__ float wsum[4];
  if ((t & 63) == 0) wsum[t >> 6] = s;
  __syncthreads();
  if (t == 0) bn[blockIdx.y * 256 + c] = wsum[0] + wsum[1] + wsum[2] + wsum[3];
}

// ---------------- BN normalize (layers 3-6 outputs, in place) ----------------

__global__ __launch_bounds__(256) void norm_kernel(
    const float* __restrict__ aBase, const float* __restrict__ bnAll,
    const float* __restrict__ gammaAll, const float* __restrict__ betaAll,
    float* __restrict__ oBase, int layer0) {
  int layer = layer0 + blockIdx.y;
  const float* a = aBase + (size_t)blockIdx.y * NN * DIM;
  const float* bn = bnAll + blockIdx.y * 256;
  const float* gamma = gammaAll + layer * 128;
  const float* beta = betaAll + layer * 128;
  float* o = oBase + (size_t)blockIdx.y * NN * DIM;
  int i = blockIdx.x * 256 + threadIdx.x;
  int f = (i & 31) * 4;
  const float inv = 1.f / (float)NN;
  float4 v = ((const float4*)a)[i];
  float r[4] = {v.x, v.y, v.z, v.w};
  #pragma unroll
  for (int j = 0; j < 4; j++) {
    float mean = bn[f + j] * inv;
    float var = bn[128 + f + j] * inv - mean * mean;
    float sc = gamma[f + j] * rsqrtf(var + BN_EPS);
    r[j] = (r[j] - mean) * sc + beta[f + j];
  }
  float4 ov; ov.x = r[0]; ov.y = r[1]; ov.z = r[2]; ov.w = r[3];
  ((float4*)o)[i] = ov;
}

// ---------------- host ----------------

extern "C" void kernel_launch(void* const* d_in, const int* in_sizes, int n_in,
                              void* d_out, int out_size, void* d_ws, size_t ws_size,
                              hipStream_t stream) {
  const float* x_in = (const float*)d_in[0];
  const int* ei = (const int*)d_in[1];
  const float* W1g = (const float*)d_in[3];
  const float* b1g = (const float*)d_in[4];
  const float* W2g = (const float*)d_in[5];
  const float* b2g = (const float*)d_in[6];
  const float* gg = (const float*)d_in[7];
  const float* bg = (const float*)d_in[8];
  float* out = (float*)d_out;

  char* ws = (char*)d_ws;
  const size_t OFF_X16 = 0;                  // 12,800,000 B
  const size_t OFF_A16 = 12800000;           // 12,800,000 B
  const size_t OFF_WB = 25600000;            // 458,752 B
  const size_t OFF_BN = 26058752;            // 4,096 B
  const size_t OFF_DEG = 26062848;           // 200,000 B
  const size_t OFF_ROW = 26262848;           // 200,004 B
  const size_t OFF_CUR = 26462852;           // 200,000 B
  const size_t OFF_ESR = 26662852;           // 2,400,000 B
  const size_t OFF_PART = 29062852;          // 4 * PART_SLOT * 4 B

  unsigned int* X16 = (unsigned int*)(ws + OFF_X16);
  unsigned int* A16 = (unsigned int*)(ws + OFF_A16);
  unsigned short* wb = (unsigned short*)(ws + OFF_WB);
  float* bn = (float*)(ws + OFF_BN);
  int* deg = (int*)(ws + OFF_DEG);
  int* rowp = (int*)(ws + OFF_ROW);
  int* cur = (int*)(ws + OFF_CUR);
  int* esrc = (int*)(ws + OFF_ESR);
  float* part = (float*)(ws + OFF_PART);
  // scan temporaries inside part region (consumed before mlp writes part)
  int* rowl = (int*)(ws + OFF_PART);
  int* bsum = (int*)(ws + OFF_PART + 800000);
  int* boff = (int*)(ws + OFF_PART + 800256);

  hipMemsetAsync(deg, 0, NN * sizeof(int), stream);
  hist_kernel<<<(NE + 255) / 256, 256, 0, stream>>>(ei, deg);
  scan_part<<<49, 256, 0, stream>>>(deg, rowl, bsum);
  scan_top<<<1, 64, 0, stream>>>(bsum, boff, rowp);
  scan_apply<<<196, 256, 0, stream>>>(rowl, boff, rowp, cur);
  bucket_kernel<<<(NE + 255) / 256, 256, 0, stream>>>(ei, cur, esrc);
  convw_kernel<<<(NLAYERS * 16384 + 255) / 256, 256, 0, stream>>>(W1g, W2g, wb);
  convx_kernel<<<NN * DIM / 4 / 256, 256, 0, stream>>>(x_in, X16);

  // layers 0..2: fp16 X updated in place (gather consumed it into A16 first)
  for (int i = 0; i < 3; i++) {
    gather_kernel<<<(NN * 64 + 255) / 256, 256, 0, stream>>>(X16, esrc, rowp, A16);
    mlp1_kernel<<<GB, 256, 0, stream>>>(
        X16, A16, wb + (size_t)i * 2 * 16384, b1g + i * 128, b2g + i * 128,
        (unsigned short*)X16, part,
        (i == 0) ? bn : bn + (i - 1) * 256,
        (i == 0) ? gg : gg + (i - 1) * 128,
        (i == 0) ? bg : bg + (i - 1) * 128, deg, i > 0 ? 1 : 0);
    reduce_kernel<<<dim3(256, 1), 256, 0, stream>>>(part, bn + i * 256);
  }
  // layers 3..6: one gather + one fused 4-layer kernel
  gather_kernel<<<(NN * 64 + 255) / 256, 256, 0, stream>>>(X16, esrc, rowp, A16);
  mlp4_kernel<<<GB, 256, 0, stream>>>(X16, A16, wb, b1g, b2g, out, part,
                                      bn + 2 * 256, gg + 2 * 128, bg + 2 * 128, deg);
  reduce_kernel<<<dim3(256, 4), 256, 0, stream>>>(part, bn);
  norm_kernel<<<dim3(NN * DIM / 4 / 256, 4), 256, 0, stream>>>(out, bn, gg, bg, out, 3);
}

// Round 12
// 467.711 us; speedup vs baseline: 1.1322x; 1.1322x over previous
//
#include <hip/hip_runtime.h>
#include <math.h>

#define NN 50000
#define NE 600000
#define DIM 128
#define NLAYERS 7
#define LDK 136           // padded LDS row stride in shorts (272B = 17*16B, keeps uint4 aligned)
#define LDF 132           // padded f32 row stride for the act-transpose staging
#define BN_EPS 1e-5f
#define GBM 391           // mlp blocks per layer (ceil(50000/128)), 512 threads each
#define PART_SLOT 200192  // per-layer part slot (floats); only GBM*256 used

typedef __attribute__((ext_vector_type(4))) float floatx4;
typedef __attribute__((ext_vector_type(8))) _Float16 half8;
typedef __attribute__((ext_vector_type(2))) _Float16 half2v;

__device__ __forceinline__ unsigned short f2h(float f) {
  _Float16 h = (_Float16)f;  // v_cvt_f16_f32, RTNE
  return __builtin_bit_cast(unsigned short, h);
}
__device__ __forceinline__ float2 up(unsigned int u) {
  half2v h = __builtin_bit_cast(half2v, u);
  return make_float2((float)h.x, (float)h.y);
}
__device__ __forceinline__ unsigned int pk(float a, float b) {
  half2v h;
  h.x = (_Float16)a;
  h.y = (_Float16)b;
  return __builtin_bit_cast(unsigned int, h);
}
// tanh(x) = 1 - 2/(e^{2x}+1); exp->v_exp_f32, rcp->v_rcp_f32. Saturates to +-1 correctly.
__device__ __forceinline__ float tanh_fast(float x) {
  float e = __expf(2.0f * x);
  return 1.0f - 2.0f * __builtin_amdgcn_rcpf(e + 1.0f);
}

// ---------------- CSR build ----------------

__global__ void hist_kernel(const int* __restrict__ ei, int* __restrict__ deg) {
  int e = blockIdx.x * 256 + threadIdx.x;
  if (e < NE) atomicAdd(&deg[ei[NE + e]], 1);
}

__global__ __launch_bounds__(256) void scan_part(const int* __restrict__ deg,
                                                 int* __restrict__ rowl,
                                                 int* __restrict__ bsum) {
  int b = blockIdx.x, t = threadIdx.x;
  int base = b * 1024 + t * 4;
  int d[4];
  #pragma unroll
  for (int j = 0; j < 4; j++) d[j] = (base + j < NN) ? deg[base + j] : 0;
  int s = d[0] + d[1] + d[2] + d[3];
  int lane = t & 63;
  int incl = s;
  #pragma unroll
  for (int off = 1; off < 64; off <<= 1) {
    int n = __shfl_up(incl, off);
    if (lane >= off) incl += n;
  }
  __shared__ int wtot[4];
  if (lane == 63) wtot[t >> 6] = incl;
  __syncthreads();
  int woff = 0;
  for (int w = 0; w < (t >> 6); w++) woff += wtot[w];
  int run = woff + incl - s;
  #pragma unroll
  for (int j = 0; j < 4; j++) {
    if (base + j < NN) rowl[base + j] = run;
    run += d[j];
  }
  if (t == 255) bsum[b] = woff + incl;
}

__global__ void scan_top(const int* __restrict__ bsum, int* __restrict__ boff,
                         int* __restrict__ row) {
  int t = threadIdx.x;  // one wave
  int v = (t < 49) ? bsum[t] : 0;
  int incl = v;
  #pragma unroll
  for (int off = 1; off < 64; off <<= 1) {
    int n = __shfl_up(incl, off);
    if (t >= off) incl += n;
  }
  if (t < 49) boff[t] = incl - v;
  if (t == 48) row[NN] = incl;
}

__global__ __launch_bounds__(256) void scan_apply(const int* __restrict__ rowl,
                                                  const int* __restrict__ boff,
                                                  int* __restrict__ row,
                                                  int* __restrict__ cur) {
  int i = blockIdx.x * 256 + threadIdx.x;
  if (i < NN) {
    int r = rowl[i] + boff[i >> 10];
    row[i] = r;
    cur[i] = r;
  }
}

__global__ void bucket_kernel(const int* __restrict__ ei, int* __restrict__ cur,
                              int* __restrict__ esrc) {
  int e = blockIdx.x * 256 + threadIdx.x;
  if (e < NE) {
    int d = ei[NE + e];
    int p = atomicAdd(&cur[d], 1);
    esrc[p] = ei[e];
  }
}

// ---------------- converts ----------------

__global__ void convw_kernel(const float* __restrict__ W1, const float* __restrict__ W2,
                             unsigned short* __restrict__ wb) {
  int i = blockIdx.x * 256 + threadIdx.x;  // 7*16384
  if (i >= NLAYERS * 16384) return;
  int l = i >> 14;
  int r = i & 16383;
  int n = r >> 7;
  int k = r & 127;
  wb[(size_t)(l * 2 + 0) * 16384 + n * 128 + k] = f2h(W1[(size_t)l * 16384 + k * 128 + n]);
  wb[(size_t)(l * 2 + 1) * 16384 + n * 128 + k] = f2h(W2[(size_t)l * 16384 + k * 128 + n]);
}

__global__ __launch_bounds__(256) void convx_kernel(const float* __restrict__ x,
                                                    unsigned int* __restrict__ x16) {
  int i = blockIdx.x * 256 + threadIdx.x;  // 1.6M exact
  float4 v = ((const float4*)x)[i];
  uint2 o;
  o.x = pk(v.x, v.y);
  o.y = pk(v.z, v.w);
  ((uint2*)x16)[i] = o;
}

// ---------------- gather (fp16): agg16[n] = sum_{e in CSR[n]} x16[esrc[e]] ----------------
// uint4 edge-slot gather (r9-proven): lane = (edge-slot g = lane>>4, 16B chunk c = lane&15),
// 4 edges/VMEM inst, 8 edges in flight; cross-slot reduce via shfl_xor(16/32).

__global__ __launch_bounds__(256) void gather_kernel(
    const unsigned int* __restrict__ x16, const int* __restrict__ esrc,
    const int* __restrict__ row, unsigned int* __restrict__ agg16) {
  int w = (blockIdx.x * 256 + threadIdx.x) >> 6;  // one wave per node
  int lane = threadIdx.x & 63;
  if (w >= NN) return;
  int g = lane >> 4;  // edge slot 0..3
  int c = lane & 15;  // uint4 chunk within row
  int s0 = row[w], s1 = row[w + 1];
  const uint4* xv4 = (const uint4*)x16;
  float a0 = 0.f, a1 = 0.f, a2 = 0.f, a3 = 0.f, a4 = 0.f, a5 = 0.f, a6 = 0.f, a7 = 0.f;
  int e = s0;
  for (; e + 7 < s1; e += 8) {  // 8 edges in flight (2 x 4-slot groups)
    int i0 = esrc[e + g];
    int i1 = esrc[e + 4 + g];
    uint4 v0 = xv4[(size_t)i0 * 16 + c];
    uint4 v1 = xv4[(size_t)i1 * 16 + c];
    float2 f;
    f = up(v0.x); a0 += f.x; a1 += f.y;
    f = up(v0.y); a2 += f.x; a3 += f.y;
    f = up(v0.z); a4 += f.x; a5 += f.y;
    f = up(v0.w); a6 += f.x; a7 += f.y;
    f = up(v1.x); a0 += f.x; a1 += f.y;
    f = up(v1.y); a2 += f.x; a3 += f.y;
    f = up(v1.z); a4 += f.x; a5 += f.y;
    f = up(v1.w); a6 += f.x; a7 += f.y;
  }
  for (; e < s1; e += 4) {  // masked 4-slot tail
    int ee = e + g;
    bool val = ee < s1;
    int idx = esrc[val ? ee : s0];
    uint4 v = xv4[(size_t)idx * 16 + c];
    if (!val) { v.x = 0u; v.y = 0u; v.z = 0u; v.w = 0u; }
    float2 f;
    f = up(v.x); a0 += f.x; a1 += f.y;
    f = up(v.y); a2 += f.x; a3 += f.y;
    f = up(v.z); a4 += f.x; a5 += f.y;
    f = up(v.w); a6 += f.x; a7 += f.y;
  }
  // reduce across edge slots: lanes {c, c+16, c+32, c+48}
  a0 += __shfl_xor(a0, 16); a0 += __shfl_xor(a0, 32);
  a1 += __shfl_xor(a1, 16); a1 += __shfl_xor(a1, 32);
  a2 += __shfl_xor(a2, 16); a2 += __shfl_xor(a2, 32);
  a3 += __shfl_xor(a3, 16); a3 += __shfl_xor(a3, 32);
  a4 += __shfl_xor(a4, 16); a4 += __shfl_xor(a4, 32);
  a5 += __shfl_xor(a5, 16); a5 += __shfl_xor(a5, 32);
  a6 += __shfl_xor(a6, 16); a6 += __shfl_xor(a6, 32);
  a7 += __shfl_xor(a7, 16); a7 += __shfl_xor(a7, 32);
  if (lane < 16) {
    uint4 o;
    o.x = pk(a0, a1);
    o.y = pk(a2, a3);
    o.z = pk(a4, a5);
    o.w = pk(a6, a7);
    ((uint4*)agg16)[(size_t)w * 16 + c] = o;
  }
}

// ---------------- single-layer MLP (layers 0-2), fp16 in/out, BN-prev folded ----------------
// 128-row tile, 512 threads (8 waves x 16 rows). Grid 391 <= 2 blocks/CU x 256 = 512
// resident -> NO tail convoy (r9's 782 vs 768 left a 14-block tail). 16 waves/CU.
// Direct global->LDS weight staging ONLY (register prefetch spills -> HBM blowup, r11).
// LDS arena 70,656B: hS[128][LDK]@0 | wS[128][LDK]@34816 | scshS@69632.
// Epilogue overlay: out fp16 in hS region; redS (8KB) in wS region.

__global__ __launch_bounds__(512) void mlp1_kernel(
    const unsigned int* __restrict__ x16, const unsigned int* __restrict__ agg16,
    const unsigned short* __restrict__ wb,  // this layer's [2][128][128] fp16 [n][k]
    const float* __restrict__ b1, const float* __restrict__ b2,
    unsigned short* __restrict__ xout16, float* __restrict__ part,
    const float* __restrict__ bnPrev, const float* __restrict__ gPrev,
    const float* __restrict__ btPrev, const int* __restrict__ deg, int hasPrev) {
  __shared__ __align__(16) unsigned char smem[70656];
  unsigned short* hS = (unsigned short*)smem;             // [128][LDK]
  unsigned short* wS = (unsigned short*)(smem + 34816);   // [128][LDK]
  float* scshS = (float*)(smem + 69632);                  // [256]
  int tid = threadIdx.x;
  int row0 = blockIdx.x * 128;

  if (tid < 128) {
    float sc = 1.f, sh = 0.f;
    if (hasPrev) {
      const float inv = 1.f / (float)NN;
      float mean = bnPrev[tid] * inv;
      float var = bnPrev[128 + tid] * inv - mean * mean;
      sc = gPrev[tid] * rsqrtf(var + BN_EPS);
      sh = btPrev[tid] - mean * sc;
    }
    scshS[tid] = sc;
    scshS[128 + tid] = sh;
  }
  __syncthreads();

  // stage h = sc*(x+agg) + (1+deg)*sh -> fp16 LDS, 16B/thread/iter
  for (int idx = tid; idx < 2048; idx += 512) {
    int r = idx >> 4;
    int c = (idx & 15) * 8;  // half index
    uint4 hv = {0u, 0u, 0u, 0u};
    if (row0 + r < NN) {
      size_t base = (size_t)(row0 + r) * 16 + (c >> 3);
      uint4 xv = ((const uint4*)x16)[base];
      uint4 av = ((const uint4*)agg16)[base];
      float dr = 1.f + (float)deg[row0 + r];
      unsigned int xs[4] = {xv.x, xv.y, xv.z, xv.w};
      unsigned int as_[4] = {av.x, av.y, av.z, av.w};
      unsigned int hs[4];
      #pragma unroll
      for (int j = 0; j < 4; j++) {
        float2 xf = up(xs[j]);
        float2 af = up(as_[j]);
        int cc = c + j * 2;
        float h0 = scshS[cc] * (xf.x + af.x) + dr * scshS[128 + cc];
        float h1 = scshS[cc + 1] * (xf.y + af.y) + dr * scshS[128 + cc + 1];
        hs[j] = pk(h0, h1);
      }
      hv.x = hs[0]; hv.y = hs[1]; hv.z = hs[2]; hv.w = hs[3];
    }
    *(uint4*)&hS[r * LDK + c] = hv;
  }
  for (int q = tid; q < 2048; q += 512) {
    int rw = q >> 4;
    int c8 = (q & 15) * 8;
    *(uint4*)&wS[rw * LDK + c8] = *(const uint4*)(wb + rw * 128 + c8);
  }
  __syncthreads();

  int lane = tid & 63;
  int wav = tid >> 6;  // 0..7, each wave owns rows [16*wav, 16*wav+16)
  int quad = lane >> 4;
  int lm = lane & 15;
  int mrow = wav * 16 + lm;
  bool wvalid = (row0 + wav * 16) < NN;  // 50000 % 16 == 0: waves all-or-nothing

  half8 aF[4];
  #pragma unroll
  for (int ks = 0; ks < 4; ks++)
    aF[ks] = *(half8*)&hS[mrow * LDK + ks * 32 + quad * 8];

  floatx4 acc[8];
  #pragma unroll
  for (int nt = 0; nt < 8; nt++) {
    float bv = b1[nt * 16 + lm];
    floatx4 c = {bv, bv, bv, bv};
    #pragma unroll
    for (int ks = 0; ks < 4; ks++) {
      half8 bf = *(half8*)&wS[(nt * 16 + lm) * LDK + ks * 32 + quad * 8];
      c = __builtin_amdgcn_mfma_f32_16x16x32_f16(aF[ks], bf, c, 0, 0, 0);
    }
    acc[nt] = c;
  }
  #pragma unroll
  for (int nt = 0; nt < 8; nt++) {
    #pragma unroll
    for (int rg = 0; rg < 4; rg++) {
      float v = acc[nt][rg];
      v = v > 0.f ? v : 0.f;
      hS[(wav * 16 + quad * 4 + rg) * LDK + nt * 16 + lm] = f2h(v);
    }
  }
  __syncthreads();
  for (int q = tid; q < 2048; q += 512) {
    int rw = q >> 4;
    int c8 = (q & 15) * 8;
    *(uint4*)&wS[rw * LDK + c8] = *(const uint4*)(wb + 16384 + rw * 128 + c8);
  }
  __syncthreads();

  // cache h1 A-fragments, then ALL GEMM2 (so hS/wS free for epilogue staging)
  half8 aG[4];
  #pragma unroll
  for (int ks = 0; ks < 4; ks++)
    aG[ks] = *(half8*)&hS[mrow * LDK + ks * 32 + quad * 8];
  #pragma unroll
  for (int nt = 0; nt < 8; nt++) {
    float bv = b2[nt * 16 + lm];
    floatx4 c = {bv, bv, bv, bv};
    #pragma unroll
    for (int ks = 0; ks < 4; ks++) {
      half8 bf = *(half8*)&wS[(nt * 16 + lm) * LDK + ks * 32 + quad * 8];
      c = __builtin_amdgcn_mfma_f32_16x16x32_f16(aG[ks], bf, c, 0, 0, 0);
    }
    acc[nt] = c;
  }

  float sArr[8], sqArr[8];
  #pragma unroll
  for (int nt = 0; nt < 8; nt++) {
    float s = 0.f, sq = 0.f;
    #pragma unroll
    for (int rg = 0; rg < 4; rg++) {
      float v = acc[nt][rg];
      v = v > 0.f ? v : 0.f;
      acc[nt][rg] = v;
      s += v;
      sq += v * v;
    }
    s += __shfl_xor(s, 16);
    s += __shfl_xor(s, 32);
    sq += __shfl_xor(sq, 16);
    sq += __shfl_xor(sq, 32);
    sArr[nt] = s;
    sqArr[nt] = sq;
  }
  __syncthreads();  // all wS(W2) + hS(h1) reads done

  // stage fp16 output into hS; redS (8 waves x 256) into wS region
  #pragma unroll
  for (int nt = 0; nt < 8; nt++) {
    #pragma unroll
    for (int rg = 0; rg < 4; rg++)
      hS[(wav * 16 + quad * 4 + rg) * LDK + nt * 16 + lm] = f2h(acc[nt][rg]);
  }
  float* redS = (float*)(smem + 34816);
  if (quad == 0) {
    #pragma unroll
    for (int nt = 0; nt < 8; nt++) {
      redS[wav * 256 + nt * 16 + lm] = wvalid ? sArr[nt] : 0.f;
      redS[wav * 256 + 128 + nt * 16 + lm] = wvalid ? sqArr[nt] : 0.f;
    }
  }
  __syncthreads();

  // vectorized store: uint4 per thread, full 256B row segments
  for (int q = tid; q < 2048; q += 512) {
    int rw = q >> 4;
    int c8 = (q & 15) * 8;
    if (row0 + rw < NN)
      *(uint4*)&xout16[(size_t)(row0 + rw) * DIM + c8] = *(uint4*)&hS[rw * LDK + c8];
  }
  if (tid < 256) {
    float v = 0.f;
    #pragma unroll
    for (int w = 0; w < 8; w++) v += redS[w * 256 + tid];
    part[(size_t)blockIdx.x * 256 + tid] = v;
  }
}

// ---------------- fused 4-layer MLP (layers 3-6): h staged once, A-frags in regs --------
// 128-row tile, 512 threads, 2 blocks/CU, no tail. Direct weight staging (no prefetch).
// LDS arena 75,776B: main hS@0|wS@34816|scshS@69632; epilogue actS[128][LDF]@0 (67,584B)
// + redS@67584 (8KB). scshS dead by epilogue (overlap safe).

__global__ __launch_bounds__(512) void mlp4_kernel(
    const unsigned int* __restrict__ x16, const unsigned int* __restrict__ agg16,
    const unsigned short* __restrict__ wbg,
    const float* __restrict__ b1g, const float* __restrict__ b2g,
    float* __restrict__ out, float* __restrict__ partBase,
    const float* __restrict__ bnPrev, const float* __restrict__ gPrev,
    const float* __restrict__ btPrev, const int* __restrict__ deg) {
  __shared__ __align__(16) unsigned char smem[75776];
  unsigned short* hS = (unsigned short*)smem;             // [128][LDK]
  unsigned short* wS = (unsigned short*)(smem + 34816);   // [128][LDK]
  float* scshS = (float*)(smem + 69632);                  // [256]
  float* actS = (float*)smem;                             // [128][LDF] epilogue
  float* redS = (float*)(smem + 67584);                   // [2048] epilogue
  int tid = threadIdx.x;
  int row0 = blockIdx.x * 128;

  if (tid < 128) {
    const float inv = 1.f / (float)NN;
    float mean = bnPrev[tid] * inv;
    float var = bnPrev[128 + tid] * inv - mean * mean;
    float sc = gPrev[tid] * rsqrtf(var + BN_EPS);
    scshS[tid] = sc;
    scshS[128 + tid] = btPrev[tid] - mean * sc;
  }
  __syncthreads();

  for (int idx = tid; idx < 2048; idx += 512) {
    int r = idx >> 4;
    int c = (idx & 15) * 8;
    uint4 hv = {0u, 0u, 0u, 0u};
    if (row0 + r < NN) {
      size_t base = (size_t)(row0 + r) * 16 + (c >> 3);
      uint4 xv = ((const uint4*)x16)[base];
      uint4 av = ((const uint4*)agg16)[base];
      float dr = 1.f + (float)deg[row0 + r];
      unsigned int xs[4] = {xv.x, xv.y, xv.z, xv.w};
      unsigned int as_[4] = {av.x, av.y, av.z, av.w};
      unsigned int hs[4];
      #pragma unroll
      for (int j = 0; j < 4; j++) {
        float2 xf = up(xs[j]);
        float2 af = up(as_[j]);
        int cc = c + j * 2;
        float h0 = scshS[cc] * (xf.x + af.x) + dr * scshS[128 + cc];
        float h1 = scshS[cc + 1] * (xf.y + af.y) + dr * scshS[128 + cc + 1];
        hs[j] = pk(h0, h1);
      }
      hv.x = hs[0]; hv.y = hs[1]; hv.z = hs[2]; hv.w = hs[3];
    }
    *(uint4*)&hS[r * LDK + c] = hv;
  }
  __syncthreads();

  int lane = tid & 63;
  int wav = tid >> 6;
  int quad = lane >> 4;
  int lm = lane & 15;
  int mrow = wav * 16 + lm;
  bool wvalid = (row0 + wav * 16) < NN;

  // A-fragments of h live in registers across all 4 layers
  half8 aF[4];
  #pragma unroll
  for (int ks = 0; ks < 4; ks++)
    aF[ks] = *(half8*)&hS[mrow * LDK + ks * 32 + quad * 8];

  #pragma unroll 1
  for (int ly = 0; ly < 4; ly++) {
    int layer = 3 + ly;
    const unsigned short* wb = wbg + (size_t)layer * 2 * 16384;
    const float* b1 = b1g + layer * 128;
    const float* b2 = b2g + layer * 128;
    float* act = out + (size_t)ly * NN * DIM;
    float* part = partBase + (size_t)ly * PART_SLOT;

    __syncthreads();  // prev iter's actS/redS reads done
    for (int q = tid; q < 2048; q += 512) {
      int rw = q >> 4;
      int c8 = (q & 15) * 8;
      *(uint4*)&wS[rw * LDK + c8] = *(const uint4*)(wb + rw * 128 + c8);
    }
    __syncthreads();

    floatx4 acc[8];
    #pragma unroll
    for (int nt = 0; nt < 8; nt++) {
      float bv = b1[nt * 16 + lm];
      floatx4 c = {bv, bv, bv, bv};
      #pragma unroll
      for (int ks = 0; ks < 4; ks++) {
        half8 bf = *(half8*)&wS[(nt * 16 + lm) * LDK + ks * 32 + quad * 8];
        c = __builtin_amdgcn_mfma_f32_16x16x32_f16(aF[ks], bf, c, 0, 0, 0);
      }
      acc[nt] = c;
    }
    #pragma unroll
    for (int nt = 0; nt < 8; nt++) {
      #pragma unroll
      for (int rg = 0; rg < 4; rg++) {
        float v = acc[nt][rg];
        v = v > 0.f ? v : 0.f;
        hS[(wav * 16 + quad * 4 + rg) * LDK + nt * 16 + lm] = f2h(v);
      }
    }
    __syncthreads();
    for (int q = tid; q < 2048; q += 512) {
      int rw = q >> 4;
      int c8 = (q & 15) * 8;
      *(uint4*)&wS[rw * LDK + c8] = *(const uint4*)(wb + 16384 + rw * 128 + c8);
    }
    __syncthreads();

    // cache h1 A-frags, then ALL GEMM2 (frees hS/wS for epilogue staging)
    half8 aG[4];
    #pragma unroll
    for (int ks = 0; ks < 4; ks++)
      aG[ks] = *(half8*)&hS[mrow * LDK + ks * 32 + quad * 8];
    #pragma unroll
    for (int nt = 0; nt < 8; nt++) {
      float bv = b2[nt * 16 + lm];
      floatx4 c = {bv, bv, bv, bv};
      #pragma unroll
      for (int ks = 0; ks < 4; ks++) {
        half8 bf = *(half8*)&wS[(nt * 16 + lm) * LDK + ks * 32 + quad * 8];
        c = __builtin_amdgcn_mfma_f32_16x16x32_f16(aG[ks], bf, c, 0, 0, 0);
      }
      acc[nt] = c;
    }

    float sArr[8], sqArr[8];
    #pragma unroll
    for (int nt = 0; nt < 8; nt++) {
      float s = 0.f, sq = 0.f;
      #pragma unroll
      for (int rg = 0; rg < 4; rg++) {
        float v = tanh_fast(acc[nt][rg]);
        acc[nt][rg] = v;
        s += v;
        sq += v * v;
      }
      s += __shfl_xor(s, 16);
      s += __shfl_xor(s, 32);
      sq += __shfl_xor(sq, 16);
      sq += __shfl_xor(sq, 32);
      sArr[nt] = s;
      sqArr[nt] = sq;
    }
    __syncthreads();  // all wS(W2) + hS(h1) reads done

    // stage f32 act into actS [128][LDF]; redS (8 waves x 256) at arena tail
    #pragma unroll
    for (int nt = 0; nt < 8; nt++) {
      #pragma unroll
      for (int rg = 0; rg < 4; rg++)
        actS[(wav * 16 + quad * 4 + rg) * LDF + nt * 16 + lm] = acc[nt][rg];
    }
    if (quad == 0) {
      #pragma unroll
      for (int nt = 0; nt < 8; nt++) {
        redS[wav * 256 + nt * 16 + lm] = wvalid ? sArr[nt] : 0.f;
        redS[wav * 256 + 128 + nt * 16 + lm] = wvalid ? sqArr[nt] : 0.f;
      }
    }
    __syncthreads();

    // vectorized store: float4 per thread, full 512B row segments
    for (int q = tid; q < 4096; q += 512) {
      int rw = q >> 5;
      int c4 = (q & 31) * 4;
      if (row0 + rw < NN)
        *(float4*)&act[(size_t)(row0 + rw) * DIM + c4] = *(float4*)&actS[rw * LDF + c4];
    }
    if (tid < 256) {
      float v = 0.f;
      #pragma unroll
      for (int w = 0; w < 8; w++) v += redS[w * 256 + tid];
      part[(size_t)blockIdx.x * 256 + tid] = v;
    }
  }
}

// ---------------- fold per-block partials -> bn[256] per layer slot ----------------

__global__ __launch_bounds__(256) void reduce_kernel(const float* __restrict__ part,
                                                     float* __restrict__ bn) {
  int c = blockIdx.x;
  int t = threadIdx.x;
  const float* p = part + (size_t)blockIdx.y * PART_SLOT + c;
  float s = 0.f;
  for (int b = t; b < GBM; b += 256) s += p[(size_t)b * 256];
  #pragma unroll
  for (int off = 1; off < 64; off <<= 1) s += __shfl_xor(s, off);
  __shared__ float wsum[4];
  if ((t & 63) == 0) wsum[t >> 6] = s;
  __syncthreads();
  if (t == 0) bn[blockIdx.y * 256 + c] = wsum[0] + wsum[1] + wsum[2] + wsum[3];
}

// ---------------- BN normalize (layers 3-6 outputs, in place) ----------------

__global__ __launch_bounds__(256) void norm_kernel(
    const float* __restrict__ aBase, const float* __restrict__ bnAll,
    const float* __restrict__ gammaAll, const float* __restrict__ betaAll,
    float* __restrict__ oBase, int layer0) {
  int layer = layer0 + blockIdx.y;
  const float* a = aBase + (size_t)blockIdx.y * NN * DIM;
  const float* bn = bnAll + blockIdx.y * 256;
  const float* gamma = gammaAll + layer * 128;
  const float* beta = betaAll + layer * 128;
  float* o = oBase + (size_t)blockIdx.y * NN * DIM;
  int i = blockIdx.x * 256 + threadIdx.x;
  int f = (i & 31) * 4;
  const float inv = 1.f / (float)NN;
  float4 v = ((const float4*)a)[i];
  float r[4] = {v.x, v.y, v.z, v.w};
  #pragma unroll
  for (int j = 0; j < 4; j++) {
    float mean = bn[f + j] * inv;
    float var = bn[128 + f + j] * inv - mean * mean;
    float sc = gamma[f + j] * rsqrtf(var + BN_EPS);
    r[j] = (r[j] - mean) * sc + beta[f + j];
  }
  float4 ov; ov.x = r[0]; ov.y = r[1]; ov.z = r[2]; ov.w = r[3];
  ((float4*)o)[i] = ov;
}

// ---------------- host ----------------

extern "C" void kernel_launch(void* const* d_in, const int* in_sizes, int n_in,
                              void* d_out, int out_size, void* d_ws, size_t ws_size,
                              hipStream_t stream) {
  const float* x_in = (const float*)d_in[0];
  const int* ei = (const int*)d_in[1];
  const float* W1g = (const float*)d_in[3];
  const float* b1g = (const float*)d_in[4];
  const float* W2g = (const float*)d_in[5];
  const float* b2g = (const float*)d_in[6];
  const float* gg = (const float*)d_in[7];
  const float* bg = (const float*)d_in[8];
  float* out = (float*)d_out;

  char* ws = (char*)d_ws;
  const size_t OFF_X16 = 0;                  // 12,800,000 B
  const size_t OFF_A16 = 12800000;           // 12,800,000 B
  const size_t OFF_WB = 25600000;            // 458,752 B
  const size_t OFF_BN = 26058752;            // 4,096 B
  const size_t OFF_DEG = 26062848;           // 200,000 B
  const size_t OFF_ROW = 26262848;           // 200,004 B
  const size_t OFF_CUR = 26462852;           // 200,000 B
  const size_t OFF_ESR = 26662852;           // 2,400,000 B
  const size_t OFF_PART = 29062852;          // 4 * PART_SLOT * 4 B

  unsigned int* X16 = (unsigned int*)(ws + OFF_X16);
  unsigned int* A16 = (unsigned int*)(ws + OFF_A16);
  unsigned short* wb = (unsigned short*)(ws + OFF_WB);
  float* bn = (float*)(ws + OFF_BN);
  int* deg = (int*)(ws + OFF_DEG);
  int* rowp = (int*)(ws + OFF_ROW);
  int* cur = (int*)(ws + OFF_CUR);
  int* esrc = (int*)(ws + OFF_ESR);
  float* part = (float*)(ws + OFF_PART);
  // scan temporaries inside part region (consumed before mlp writes part)
  int* rowl = (int*)(ws + OFF_PART);
  int* bsum = (int*)(ws + OFF_PART + 800000);
  int* boff = (int*)(ws + OFF_PART + 800256);

  hipMemsetAsync(deg, 0, NN * sizeof(int), stream);
  hist_kernel<<<(NE + 255) / 256, 256, 0, stream>>>(ei, deg);
  scan_part<<<49, 256, 0, stream>>>(deg, rowl, bsum);
  scan_top<<<1, 64, 0, stream>>>(bsum, boff, rowp);
  scan_apply<<<196, 256, 0, stream>>>(rowl, boff, rowp, cur);
  bucket_kernel<<<(NE + 255) / 256, 256, 0, stream>>>(ei, cur, esrc);
  convw_kernel<<<(NLAYERS * 16384 + 255) / 256, 256, 0, stream>>>(W1g, W2g, wb);
  convx_kernel<<<NN * DIM / 4 / 256, 256, 0, stream>>>(x_in, X16);

  // layers 0..2: fp16 X updated in place (gather consumed it into A16 first)
  for (int i = 0; i < 3; i++) {
    gather_kernel<<<(NN * 64 + 255) / 256, 256, 0, stream>>>(X16, esrc, rowp, A16);
    mlp1_kernel<<<GBM, 512, 0, stream>>>(
        X16, A16, wb + (size_t)i * 2 * 16384, b1g + i * 128, b2g + i * 128,
        (unsigned short*)X16, part,
        (i == 0) ? bn : bn + (i - 1) * 256,
        (i == 0) ? gg : gg + (i - 1) * 128,
        (i == 0) ? bg : bg + (i - 1) * 128, deg, i > 0 ? 1 : 0);
    reduce_kernel<<<dim3(256, 1), 256, 0, stream>>>(part, bn + i * 256);
  }
  // layers 3..6: one gather + one fused 4-layer kernel
  gather_kernel<<<(NN * 64 + 255) / 256, 256, 0, stream>>>(X16, esrc, rowp, A16);
  mlp4_kernel<<<GBM, 512, 0, stream>>>(X16, A16, wb, b1g, b2g, out, part,
                                       bn + 2 * 256, gg + 2 * 128, bg + 2 * 128, deg);
  reduce_kernel<<<dim3(256, 4), 256, 0, stream>>>(part, bn);
  norm_kernel<<<dim3(NN * DIM / 4 / 256, 4), 256, 0, stream>>>(out, bn, gg, bg, out, 3);
}